// Round 3
// baseline (166.775 us; speedup 1.0000x reference)
//
#include <hip/hip_runtime.h>

// Problem constants (fixed by setup_inputs)
#define NNODES 27648
#define NEDGES 442368
#define FIN    256
#define HC     512
#define NH     4
#define CDIM   128
#define NAG    48
#define NGRP   12
#define N2     2304    // 48*48
#define NOUT   576     // 12*48
#define CAP    128     // max edges kept per output row (Poisson mean ~16)
#define EDIM   16
#define NBUCK  32      // easum atomic buckets

__device__ __forceinline__ float lrelu(float v, float s){ return v > 0.0f ? v : s * v; }

__device__ __forceinline__ float wsum(float v){
  #pragma unroll
  for (int off = 32; off; off >>= 1) v += __shfl_xor(v, off, 64);
  return v;
}
__device__ __forceinline__ float wmax(float v){
  #pragma unroll
  for (int off = 32; off; off >>= 1) v = fmaxf(v, __shfl_xor(v, off, 64));
  return v;
}

// K1: blocks 0..1727: bin diagonal-dst edges into slist2=(src,e) AND column-sum
//     their own 16KB slice of edge_attr into bucketed easum32.
//     blocks 1728..1738: ws/wd/we precompute (independent).
//     counts + easum32 pre-zeroed by a hipMemsetAsync node.
__global__ __launch_bounds__(256) void k_prescan(
    const float* __restrict__ W, const float* __restrict__ att_src,
    const float* __restrict__ att_dst, const float* __restrict__ W_edge,
    const float* __restrict__ att_edge,
    const int* __restrict__ ei, const float* __restrict__ ea,
    float* __restrict__ ws_, float* __restrict__ wd_, float* __restrict__ we_,
    float* __restrict__ easum32, int* __restrict__ counts,
    int2* __restrict__ slist2){
  __shared__ float4 red[16];
  int b = blockIdx.x, tid = threadIdx.x;
  if (b < NEDGES/256){
    int e = b*256 + tid;
    int dst = ei[NEDGES + e];
    int r = dst % N2;
    if (r % 49 == 0){
      int row = (dst / N2) * NAG + r / 49;
      int pos = atomicAdd(&counts[row], 1);
      if (pos < CAP) slist2[row*CAP + pos] = make_int2(ei[e], e);
    }
    // mean partial over this block's 256 edges (16 KB contiguous)
    const float4* p4 = (const float4*)ea + (size_t)b*1024;
    float4 acc = p4[tid];
    float4 v1 = p4[tid+256], v2 = p4[tid+512], v3 = p4[tid+768];
    acc.x += v1.x+v2.x+v3.x; acc.y += v1.y+v2.y+v3.y;
    acc.z += v1.z+v2.z+v3.z; acc.w += v1.w+v2.w+v3.w;
    // reduce across lanes sharing lane&3 (col-group invariant: strides %4==0)
    #pragma unroll
    for (int off = 4; off <= 32; off <<= 1){
      acc.x += __shfl_xor(acc.x, off, 64);
      acc.y += __shfl_xor(acc.y, off, 64);
      acc.z += __shfl_xor(acc.z, off, 64);
      acc.w += __shfl_xor(acc.w, off, 64);
    }
    int lane = tid & 63, wave = tid >> 6;
    if (lane < 4) red[wave*4 + lane] = acc;
    __syncthreads();
    if (tid < 4){
      float4 t = red[tid], u = red[4+tid], v = red[8+tid], w = red[12+tid];
      t.x += u.x+v.x+w.x; t.y += u.y+v.y+w.y;
      t.z += u.z+v.z+w.z; t.w += u.w+v.w+w.w;
      float* dp = easum32 + (b & (NBUCK-1))*16 + tid*4;
      atomicAdd(dp+0, t.x); atomicAdd(dp+1, t.y);
      atomicAdd(dp+2, t.z); atomicAdd(dp+3, t.w);
    }
  } else {
    int g = (b - NEDGES/256)*256 + tid;
    if (g < 1024) {
      int f = g >> 2, h = g & 3;
      const float4* wp = (const float4*)(W + f*HC + h*CDIM);
      const float4* ap = (const float4*)(att_src + h*CDIM);
      float s = 0.f;
      #pragma unroll 8
      for (int c4 = 0; c4 < CDIM/4; c4++){
        float4 wv = wp[c4], av = ap[c4];
        s += wv.x*av.x + wv.y*av.y + wv.z*av.z + wv.w*av.w;
      }
      ws_[g] = s;
    } else if (g < 2048) {
      int gg = g - 1024; int f = gg >> 2, h = gg & 3;
      const float4* wp = (const float4*)(W + f*HC + h*CDIM);
      const float4* ap = (const float4*)(att_dst + h*CDIM);
      float s = 0.f;
      #pragma unroll 8
      for (int c4 = 0; c4 < CDIM/4; c4++){
        float4 wv = wp[c4], av = ap[c4];
        s += wv.x*av.x + wv.y*av.y + wv.z*av.z + wv.w*av.w;
      }
      wd_[gg] = s;
    } else if (g < 2112) {
      int gg = g - 2048; int d = gg >> 2, h = gg & 3;
      const float4* wp = (const float4*)(W_edge + d*HC + h*CDIM);
      const float4* ap = (const float4*)(att_edge + h*CDIM);
      float s = 0.f;
      #pragma unroll 8
      for (int c4 = 0; c4 < CDIM/4; c4++){
        float4 wv = wp[c4], av = ap[c4];
        s += wv.x*av.x + wv.y*av.y + wv.z*av.z + wv.w*av.w;
      }
      we_[gg] = s;
    }
  }
}

// K2: per output row: logits (a_src + a_edge fused in one wsum) -> segment
//     softmax -> z[row,h,:] = sum_e alpha * x[src]
__global__ __launch_bounds__(256) void k_attn(const float* __restrict__ x,
    const float* __restrict__ ws_, const float* __restrict__ wd_,
    const float* __restrict__ we_, const float* __restrict__ easum32,
    const int* __restrict__ counts, const int2* __restrict__ slist2,
    const float* __restrict__ ea, float* __restrict__ z){
  __shared__ float lg[(CAP+1)*4];
  __shared__ int   srcs[CAP];
  __shared__ float adst_s[4];
  int row = blockIdx.x;
  int g = row / NAG, j = row - g*NAG;
  int dst = g*N2 + j*49;
  int tid = threadIdx.x;
  int lane = tid & 63, wave = tid >> 6;
  int k = counts[row]; if (k > CAP) k = CAP;

  float4 wev = make_float4(0.f, 0.f, 0.f, 0.f);
  if (lane < 16) wev = *(const float4*)(we_ + lane*4);

  // per-lane slice of ws (f = lane*4+q, all 4 heads)
  float wsr[4][4];
  #pragma unroll
  for (int q = 0; q < 4; q++){
    float4 t = *(const float4*)(ws_ + (lane*4+q)*4);
    wsr[q][0]=t.x; wsr[q][1]=t.y; wsr[q][2]=t.z; wsr[q][3]=t.w;
  }

  // edges round-robin over 4 waves; a_edge folded into the same wave-sum
  for (int i = wave; i < k; i += 4){
    int2 se = slist2[row*CAP + i];
    float eav = (lane < 16) ? ea[(size_t)se.y*EDIM + lane] : 0.f;
    float4 xv = *(const float4*)(x + (size_t)se.x*FIN + lane*4);
    float p0 = xv.x*wsr[0][0] + xv.y*wsr[1][0] + xv.z*wsr[2][0] + xv.w*wsr[3][0] + eav*wev.x;
    float p1 = xv.x*wsr[0][1] + xv.y*wsr[1][1] + xv.z*wsr[2][1] + xv.w*wsr[3][1] + eav*wev.y;
    float p2 = xv.x*wsr[0][2] + xv.y*wsr[1][2] + xv.z*wsr[2][2] + xv.w*wsr[3][2] + eav*wev.z;
    float p3 = xv.x*wsr[0][3] + xv.y*wsr[1][3] + xv.z*wsr[2][3] + xv.w*wsr[3][3] + eav*wev.w;
    p0 = wsum(p0); p1 = wsum(p1); p2 = wsum(p2); p3 = wsum(p3);
    if (lane == 0){
      srcs[i] = se.x;
      lg[i*4+0] = p0; lg[i*4+1] = p1; lg[i*4+2] = p2; lg[i*4+3] = p3;
    }
  }

  // wave 0: a_dst, self-loop logit (a_src(dst) + mean_ea @ we)
  if (wave == 0){
    float wdr[4][4];
    #pragma unroll
    for (int q = 0; q < 4; q++){
      float4 t = *(const float4*)(wd_ + (lane*4+q)*4);
      wdr[q][0]=t.x; wdr[q][1]=t.y; wdr[q][2]=t.z; wdr[q][3]=t.w;
    }
    float4 xv = *(const float4*)(x + (size_t)dst*FIN + lane*4);
    float pd[4], ps[4];
    #pragma unroll
    for (int h = 0; h < 4; h++){
      pd[h] = xv.x*wdr[0][h] + xv.y*wdr[1][h] + xv.z*wdr[2][h] + xv.w*wdr[3][h];
      ps[h] = xv.x*wsr[0][h] + xv.y*wsr[1][h] + xv.z*wsr[2][h] + xv.w*wsr[3][h];
    }
    float s = 0.f;
    if (lane < 16){
      #pragma unroll
      for (int bb = 0; bb < NBUCK; bb++) s += easum32[bb*16 + lane];
    }
    float md = s * (1.0f/(float)NEDGES);
    float al[4];
    al[0] = wsum(md*wev.x); al[1] = wsum(md*wev.y);
    al[2] = wsum(md*wev.z); al[3] = wsum(md*wev.w);
    #pragma unroll
    for (int h = 0; h < 4; h++){ pd[h] = wsum(pd[h]); ps[h] = wsum(ps[h]); }
    if (lane == 0){
      #pragma unroll
      for (int h = 0; h < 4; h++){
        adst_s[h] = pd[h];
        lg[k*4+h] = ps[h] + al[h];
      }
    }
  }
  __syncthreads();

  // segment softmax: wave w handles head w over k+1 entries
  {
    int h = wave;
    float ad = adst_s[h];
    float m = -1e30f;
    for (int i = lane; i <= k; i += 64){
      float v = lrelu(lg[i*4+h] + ad, 0.2f);
      lg[i*4+h] = v;
      m = fmaxf(m, v);
    }
    m = wmax(m);
    float s = 0.f;
    for (int i = lane; i <= k; i += 64){
      float e = __expf(lg[i*4+h] - m);
      lg[i*4+h] = e;
      s += e;
    }
    s = wsum(s);
    float inv = 1.0f/(s + 1e-16f);
    for (int i = lane; i <= k; i += 64) lg[i*4+h] *= inv;
  }
  __syncthreads();

  // z accumulation: thread = feature f
  int f = tid;
  float a0=0.f,a1=0.f,a2=0.f,a3=0.f;
  for (int i = 0; i < k; i++){
    float xv = x[(size_t)srcs[i]*FIN + f];
    a0 += lg[i*4+0]*xv; a1 += lg[i*4+1]*xv; a2 += lg[i*4+2]*xv; a3 += lg[i*4+3]*xv;
  }
  {
    float xv = x[(size_t)dst*FIN + f];
    a0 += lg[k*4+0]*xv; a1 += lg[k*4+1]*xv; a2 += lg[k*4+2]*xv; a3 += lg[k*4+3]*xv;
  }
  float* zp = z + (size_t)row*1024;
  zp[0*256+f]=a0; zp[1*256+f]=a1; zp[2*256+f]=a2; zp[3*256+f]=a3;
}

// K3: fused MLP per 4 rows: h2 = lrelu(z@W+bias) kept in LDS, then
//     out = lrelu(h2@fcW+fcb). No h2 global round-trip.
__global__ __launch_bounds__(256) void k_mlp(const float* __restrict__ z,
    const float* __restrict__ W, const float* __restrict__ bias,
    const float* __restrict__ fcW, const float* __restrict__ fcb,
    float* __restrict__ out){
  __shared__ float zs[4*1024];
  __shared__ float hs[4*512];
  int base = blockIdx.x * 4;     // 144 blocks
  int tid = threadIdx.x;
  {
    const float4* sp = (const float4*)(z + (size_t)base*1024);
    float4* dp = (float4*)zs;
    #pragma unroll
    for (int i = 0; i < 4; i++) dp[tid + i*256] = sp[tid + i*256];
  }
  __syncthreads();
  // stage 1: h2[r][o] for o = h*128 + c and o+64  (h = tid>>6 wave-uniform)
  {
    int h = tid >> 6, c = tid & 63;
    int o0 = h*CDIM + c, o1 = o0 + 64;
    float a0[4] = {0,0,0,0}, a1[4] = {0,0,0,0};
    for (int k0 = 0; k0 < 256; k0 += 4){
      float w00 = W[(size_t)(k0+0)*HC + o0], w10 = W[(size_t)(k0+0)*HC + o1];
      float w01 = W[(size_t)(k0+1)*HC + o0], w11 = W[(size_t)(k0+1)*HC + o1];
      float w02 = W[(size_t)(k0+2)*HC + o0], w12 = W[(size_t)(k0+2)*HC + o1];
      float w03 = W[(size_t)(k0+3)*HC + o0], w13 = W[(size_t)(k0+3)*HC + o1];
      #pragma unroll
      for (int r = 0; r < 4; r++){
        float4 zv = *(const float4*)&zs[r*1024 + h*256 + k0];
        a0[r] += zv.x*w00 + zv.y*w01 + zv.z*w02 + zv.w*w03;
        a1[r] += zv.x*w10 + zv.y*w11 + zv.z*w12 + zv.w*w13;
      }
    }
    float b0 = bias[o0], b1 = bias[o1];
    #pragma unroll
    for (int r = 0; r < 4; r++){
      hs[r*HC + o0] = lrelu(a0[r] + b0, 0.01f);
      hs[r*HC + o1] = lrelu(a1[r] + b1, 0.01f);
    }
  }
  __syncthreads();
  // stage 2: out[r][j], j = tid
  {
    int j = tid;
    float acc[4] = {0,0,0,0};
    for (int q0 = 0; q0 < 512; q0 += 4){
      float f0 = fcW[(size_t)(q0+0)*256 + j];
      float f1 = fcW[(size_t)(q0+1)*256 + j];
      float f2 = fcW[(size_t)(q0+2)*256 + j];
      float f3 = fcW[(size_t)(q0+3)*256 + j];
      #pragma unroll
      for (int r = 0; r < 4; r++){
        float4 hv = *(const float4*)&hs[r*HC + q0];
        acc[r] += hv.x*f0 + hv.y*f1 + hv.z*f2 + hv.w*f3;
      }
    }
    float bj = fcb[j];
    #pragma unroll
    for (int r = 0; r < 4; r++)
      out[(size_t)(base+r)*256 + j] = lrelu(acc[r] + bj, 0.01f);
  }
}

extern "C" void kernel_launch(void* const* d_in, const int* in_sizes, int n_in,
                              void* d_out, int out_size, void* d_ws, size_t ws_size,
                              hipStream_t stream) {
  const float* x        = (const float*)d_in[0];
  const int*   ei       = (const int*)  d_in[1];
  const float* ea       = (const float*)d_in[2];
  // d_in[3]=num_groups, d_in[4]=agents_per_group (fixed: 12, 48)
  const float* W        = (const float*)d_in[5];
  const float* att_src  = (const float*)d_in[6];
  const float* att_dst  = (const float*)d_in[7];
  const float* W_edge   = (const float*)d_in[8];
  const float* att_edge = (const float*)d_in[9];
  const float* bias     = (const float*)d_in[10];
  const float* fcW      = (const float*)d_in[11];
  const float* fcb      = (const float*)d_in[12];
  float* out = (float*)d_out;

  float* w = (float*)d_ws;
  float* ws_     = w;                    // 1024
  float* wd_     = w + 1024;             // 1024
  float* we_     = w + 2048;             // 64
  float* easum32 = w + 2112;             // 32*16 = 512  (zeroed)
  int*   counts  = (int*)(w + 2624);     // 576          (zeroed)
  int2*  slist2  = (int2*)(w + 3200);    // 576*128 int2 = 147456 floats
  float* z       = w + 150656;           // 576*1024 = 589824  (total ~2.9 MB)

  hipMemsetAsync(w + 2112, 0, (512 + 576) * sizeof(float), stream);
  k_prescan<<<NEDGES/256 + 11, 256, 0, stream>>>(
      W, att_src, att_dst, W_edge, att_edge, ei, ea,
      ws_, wd_, we_, easum32, counts, slist2);
  k_attn<<<NOUT, 256, 0, stream>>>(x, ws_, wd_, we_, easum32, counts, slist2, ea, z);
  k_mlp<<<144, 256, 0, stream>>>(z, W, bias, fcW, fcb, out);
}